// Round 1
// baseline (481.227 us; speedup 1.0000x reference)
//
#include <hip/hip_runtime.h>
#include <hip/hip_bf16.h>

// Problem constants
#define N_ 64
#define H_ 256
#define W_ 256
#define C_ 16
#define O_ 16
#define KS 3

// Tile config: 32 wide x 16 tall output tile, 256 threads, 2 pixels/thread
#define TW 32
#define TH 16
#define HALO_W (TW + 2)   // 34
#define HALO_H (TH + 2)   // 18
#define PSTRIDE 20        // floats per pixel slot in LDS (16 + 4 pad -> bank-balanced b128)

__global__ __launch_bounds__(256, 3)
void sep_conv_kernel(const float* __restrict__ in,
                     const float* __restrict__ u,   // (O,K) = (16,3)
                     const float* __restrict__ v,   // (O,K)
                     const float* __restrict__ w,   // (O,C) = (16,16)
                     const float* __restrict__ b,   // (O)
                     float* __restrict__ out) {
    __shared__ float t_lds[HALO_H * HALO_W * PSTRIDE];  // 48960 B

    const int tid = threadIdx.x;
    const int x0 = blockIdx.x * TW;
    const int y0 = blockIdx.y * TH;
    const int n  = blockIdx.z;

    const float* inbase = in + (size_t)n * H_ * W_ * C_;

    // ---- Stage 1: compute t = channel-mix into LDS (with halo, SAME padding) ----
    for (int p = tid; p < HALO_H * HALO_W; p += 256) {
        const int r = p / HALO_W;
        const int c = p - r * HALO_W;
        const int gy = y0 + r - 1;
        const int gx = x0 + c - 1;
        float tv[16];
        if ((unsigned)gy < (unsigned)H_ && (unsigned)gx < (unsigned)W_) {
            const float4* s4 = (const float4*)(inbase + ((size_t)gy * W_ + gx) * C_);
            const float4 a0 = s4[0];
            const float4 a1 = s4[1];
            const float4 a2 = s4[2];
            const float4 a3 = s4[3];
            float iv[16] = {a0.x, a0.y, a0.z, a0.w,
                            a1.x, a1.y, a1.z, a1.w,
                            a2.x, a2.y, a2.z, a2.w,
                            a3.x, a3.y, a3.z, a3.w};
            #pragma unroll
            for (int l = 0; l < 16; ++l) {
                float s = 0.f;
                #pragma unroll
                for (int k = 0; k < 16; ++k) {
                    s = fmaf(w[l * 16 + k], iv[k], s);  // w uniform -> s_load expected
                }
                tv[l] = s;
            }
        } else {
            #pragma unroll
            for (int l = 0; l < 16; ++l) tv[l] = 0.f;
        }
        float4* d4 = (float4*)&t_lds[p * PSTRIDE];
        d4[0] = make_float4(tv[0],  tv[1],  tv[2],  tv[3]);
        d4[1] = make_float4(tv[4],  tv[5],  tv[6],  tv[7]);
        d4[2] = make_float4(tv[8],  tv[9],  tv[10], tv[11]);
        d4[3] = make_float4(tv[12], tv[13], tv[14], tv[15]);
    }
    __syncthreads();

    // ---- Stage 2: separable 3x3 depthwise conv on t, bias + relu, store ----
    const int tx  = tid & (TW - 1);   // 0..31
    const int tyb = tid >> 5;         // 0..7
    #pragma unroll
    for (int pp = 0; pp < 2; ++pp) {
        const int ty = tyb + pp * 8;  // 0..15
        float acc[16];
        #pragma unroll
        for (int l = 0; l < 16; ++l) acc[l] = 0.f;

        #pragma unroll
        for (int i = 0; i < 3; ++i) {
            float h[16];
            #pragma unroll
            for (int l = 0; l < 16; ++l) h[l] = 0.f;
            #pragma unroll
            for (int j = 0; j < 3; ++j) {
                const float4* tp =
                    (const float4*)&t_lds[((ty + i) * HALO_W + (tx + j)) * PSTRIDE];
                const float4 a0 = tp[0];
                const float4 a1 = tp[1];
                const float4 a2 = tp[2];
                const float4 a3 = tp[3];
                const float tvv[16] = {a0.x, a0.y, a0.z, a0.w,
                                       a1.x, a1.y, a1.z, a1.w,
                                       a2.x, a2.y, a2.z, a2.w,
                                       a3.x, a3.y, a3.z, a3.w};
                #pragma unroll
                for (int l = 0; l < 16; ++l) {
                    h[l] = fmaf(u[l * 3 + j], tvv[l], h[l]);  // u uniform -> sgpr
                }
            }
            #pragma unroll
            for (int l = 0; l < 16; ++l) {
                acc[l] = fmaf(v[l * 3 + i], h[l], acc[l]);    // v uniform -> sgpr
            }
        }

        float r[16];
        #pragma unroll
        for (int l = 0; l < 16; ++l) {
            float val = acc[l] + b[l];
            r[l] = val > 0.f ? val : 0.f;
        }
        float4* o4 = (float4*)(out + (((size_t)n * H_ + (y0 + ty)) * W_ + (x0 + tx)) * C_);
        o4[0] = make_float4(r[0],  r[1],  r[2],  r[3]);
        o4[1] = make_float4(r[4],  r[5],  r[6],  r[7]);
        o4[2] = make_float4(r[8],  r[9],  r[10], r[11]);
        o4[3] = make_float4(r[12], r[13], r[14], r[15]);
    }
}

extern "C" void kernel_launch(void* const* d_in, const int* in_sizes, int n_in,
                              void* d_out, int out_size, void* d_ws, size_t ws_size,
                              hipStream_t stream) {
    const float* in = (const float*)d_in[0];
    const float* u  = (const float*)d_in[1];
    const float* v  = (const float*)d_in[2];
    const float* w  = (const float*)d_in[3];
    const float* b  = (const float*)d_in[4];
    float* out = (float*)d_out;

    dim3 grid(W_ / TW, H_ / TH, N_);  // 8 x 16 x 64
    dim3 block(256);
    sep_conv_kernel<<<grid, block, 0, stream>>>(in, u, v, w, b, out);
}

// Round 2
// 463.479 us; speedup vs baseline: 1.0383x; 1.0383x over previous
//
#include <hip/hip_runtime.h>
#include <hip/hip_bf16.h>

// Problem constants
#define N_ 64
#define H_ 256
#define W_ 256
#define C_ 16
#define O_ 16

// Tile config: 32 wide x 8 tall output tile, 256 threads, 1 output pixel/thread
#define TW 32
#define TH 8
#define HALO_W (TW + 2)   // 34
#define HALO_H (TH + 2)   // 10
#define NHALO (HALO_W * HALO_H)  // 340 staging pixels
#define PSTRIDE 20        // floats per pixel slot in LDS (16 + 4 pad); measured 0 bank conflicts

__global__ __launch_bounds__(256, 5)
void sep_conv_kernel(const float* __restrict__ in,
                     const float* __restrict__ u,   // (O,K) = (16,3)
                     const float* __restrict__ v,   // (O,K)
                     const float* __restrict__ w,   // (O,C) = (16,16)
                     const float* __restrict__ b,   // (O)
                     float* __restrict__ out) {
    __shared__ float t_lds[NHALO * PSTRIDE];  // 340*20*4 = 27,200 B -> 5 blocks/CU

    const int tid = threadIdx.x;
    const int x0 = blockIdx.x * TW;
    const int y0 = blockIdx.y * TH;
    const int n  = blockIdx.z;

    const float* inbase = in + (size_t)n * H_ * W_ * C_;

    // ---- Stage 1: channel-mix t = in . w^T into LDS (halo, SAME padding) ----
    // Thread handles staging pixels tid and tid+256. Issue ALL global loads
    // first (8x dwordx4 in flight), then compute, then write LDS.
    const int p0 = tid;         // < 340 always
    const int p1 = tid + 256;   // valid for tid < 84
    const bool has1 = (p1 < NHALO);

    const int r0 = p0 / HALO_W, c0 = p0 - r0 * HALO_W;
    const int r1 = p1 / HALO_W, c1 = p1 - r1 * HALO_W;
    const int gy0 = y0 + r0 - 1, gx0 = x0 + c0 - 1;
    const int gy1 = y0 + r1 - 1, gx1 = x0 + c1 - 1;
    const bool in0 = (unsigned)gy0 < (unsigned)H_ && (unsigned)gx0 < (unsigned)W_;
    const bool in1 = has1 && (unsigned)gy1 < (unsigned)H_ && (unsigned)gx1 < (unsigned)W_;

    float4 A[4], B[4];
    #pragma unroll
    for (int q = 0; q < 4; ++q) A[q] = make_float4(0.f, 0.f, 0.f, 0.f);
    #pragma unroll
    for (int q = 0; q < 4; ++q) B[q] = make_float4(0.f, 0.f, 0.f, 0.f);

    if (in0) {
        const float4* s4 = (const float4*)(inbase + ((size_t)gy0 * W_ + gx0) * C_);
        #pragma unroll
        for (int q = 0; q < 4; ++q) A[q] = s4[q];
    }
    if (in1) {
        const float4* s4 = (const float4*)(inbase + ((size_t)gy1 * W_ + gx1) * C_);
        #pragma unroll
        for (int q = 0; q < 4; ++q) B[q] = s4[q];
    }

    {
        const float iv0[16] = {A[0].x, A[0].y, A[0].z, A[0].w,
                               A[1].x, A[1].y, A[1].z, A[1].w,
                               A[2].x, A[2].y, A[2].z, A[2].w,
                               A[3].x, A[3].y, A[3].z, A[3].w};
        float tv[16];
        #pragma unroll
        for (int l = 0; l < 16; ++l) {
            float s = 0.f;
            #pragma unroll
            for (int k = 0; k < 16; ++k) s = fmaf(w[l * 16 + k], iv0[k], s);
            tv[l] = s;
        }
        float4* d4 = (float4*)&t_lds[p0 * PSTRIDE];
        d4[0] = make_float4(tv[0],  tv[1],  tv[2],  tv[3]);
        d4[1] = make_float4(tv[4],  tv[5],  tv[6],  tv[7]);
        d4[2] = make_float4(tv[8],  tv[9],  tv[10], tv[11]);
        d4[3] = make_float4(tv[12], tv[13], tv[14], tv[15]);
    }
    if (has1) {
        const float iv1[16] = {B[0].x, B[0].y, B[0].z, B[0].w,
                               B[1].x, B[1].y, B[1].z, B[1].w,
                               B[2].x, B[2].y, B[2].z, B[2].w,
                               B[3].x, B[3].y, B[3].z, B[3].w};
        float tv[16];
        #pragma unroll
        for (int l = 0; l < 16; ++l) {
            float s = 0.f;
            #pragma unroll
            for (int k = 0; k < 16; ++k) s = fmaf(w[l * 16 + k], iv1[k], s);
            tv[l] = s;
        }
        float4* d4 = (float4*)&t_lds[p1 * PSTRIDE];
        d4[0] = make_float4(tv[0],  tv[1],  tv[2],  tv[3]);
        d4[1] = make_float4(tv[4],  tv[5],  tv[6],  tv[7]);
        d4[2] = make_float4(tv[8],  tv[9],  tv[10], tv[11]);
        d4[3] = make_float4(tv[12], tv[13], tv[14], tv[15]);
    }
    __syncthreads();

    // ---- Stage 2: separable 3x3 depthwise conv on t, bias + relu, store ----
    const int tx = tid & (TW - 1);   // 0..31
    const int ty = tid >> 5;         // 0..7

    float acc[16];
    #pragma unroll
    for (int l = 0; l < 16; ++l) acc[l] = 0.f;

    #pragma unroll
    for (int i = 0; i < 3; ++i) {
        float h[16];
        #pragma unroll
        for (int l = 0; l < 16; ++l) h[l] = 0.f;
        #pragma unroll
        for (int j = 0; j < 3; ++j) {
            const float4* tp =
                (const float4*)&t_lds[((ty + i) * HALO_W + (tx + j)) * PSTRIDE];
            const float4 a0 = tp[0];
            const float4 a1 = tp[1];
            const float4 a2 = tp[2];
            const float4 a3 = tp[3];
            const float tvv[16] = {a0.x, a0.y, a0.z, a0.w,
                                   a1.x, a1.y, a1.z, a1.w,
                                   a2.x, a2.y, a2.z, a2.w,
                                   a3.x, a3.y, a3.z, a3.w};
            #pragma unroll
            for (int l = 0; l < 16; ++l) {
                h[l] = fmaf(u[l * 3 + j], tvv[l], h[l]);
            }
        }
        #pragma unroll
        for (int l = 0; l < 16; ++l) {
            acc[l] = fmaf(v[l * 3 + i], h[l], acc[l]);
        }
    }

    float r[16];
    #pragma unroll
    for (int l = 0; l < 16; ++l) {
        float val = acc[l] + b[l];
        r[l] = val > 0.f ? val : 0.f;
    }
    float4* o4 = (float4*)(out + (((size_t)n * H_ + (y0 + ty)) * W_ + (x0 + tx)) * C_);
    o4[0] = make_float4(r[0],  r[1],  r[2],  r[3]);
    o4[1] = make_float4(r[4],  r[5],  r[6],  r[7]);
    o4[2] = make_float4(r[8],  r[9],  r[10], r[11]);
    o4[3] = make_float4(r[12], r[13], r[14], r[15]);
}

extern "C" void kernel_launch(void* const* d_in, const int* in_sizes, int n_in,
                              void* d_out, int out_size, void* d_ws, size_t ws_size,
                              hipStream_t stream) {
    const float* in = (const float*)d_in[0];
    const float* u  = (const float*)d_in[1];
    const float* v  = (const float*)d_in[2];
    const float* w  = (const float*)d_in[3];
    const float* b  = (const float*)d_in[4];
    float* out = (float*)d_out;

    dim3 grid(W_ / TW, H_ / TH, N_);  // 8 x 32 x 64
    dim3 block(256);
    sep_conv_kernel<<<grid, block, 0, stream>>>(in, u, v, w, b, out);
}